// Round 7
// baseline (139.366 us; speedup 1.0000x reference)
//
#include <hip/hip_runtime.h>
#include <hip/hip_bf16.h>
#include <math.h>

#define NATOMS 1280
#define NHEAD 4
#define DHEAD 16
#define EEDGE 5120
#define MKV 12800
#define NLAYERS 4
#define NGRAPH 32
#define NPG 40      // atoms per graph
#define MPG 400     // kv per graph
#define QH 10       // q rows per attention block (quarter graph)

// ---- one precompute kernel: agg zero + EW GEMM + KV GEMM --------------------
// blocks [0,320): EW tiles; [320,1120): KV tiles; [1120,1200): agg zeroing
__global__ __launch_bounds__(256) void precompute_kernel(
    const float* __restrict__ edge_attr, const float* __restrict__ Kin,
    const float* __restrict__ Vin, const float* __restrict__ We,
    const float* __restrict__ Wk, const float* __restrict__ Wv,
    float* __restrict__ EW, float* __restrict__ Kh, float* __restrict__ Vh,
    float* __restrict__ agg) {
  __shared__ float aT[64][132];  // A tile transposed [k][row], padded
  __shared__ float wS[64][64];
  const int b = blockIdx.x, t = threadIdx.x;

  if (b < 320) {  // ---- EW[l] = edge_attr @ We[l], 64-row tiles, K=16 ----
    int l = b / 80, et = b % 80;
    const float* A = edge_attr + (size_t)et * 64 * 16;
    const float* W = We + l * 1024;
    float* C = EW + ((size_t)l * EEDGE + et * 64) * 64;
    {
      int r = t >> 2, c0 = (t & 3) * 4;
      float4 v = *(const float4*)(A + r * 16 + c0);
      aT[c0 + 0][r] = v.x; aT[c0 + 1][r] = v.y;
      aT[c0 + 2][r] = v.z; aT[c0 + 3][r] = v.w;
      float4 w = ((const float4*)W)[t];
      *(float4*)&wS[t >> 4][(t & 15) * 4] = w;
    }
    __syncthreads();
    const int rb = (t >> 4) * 4, cb = (t & 15) * 4;
    float acc[4][4] = {};
#pragma unroll
    for (int k = 0; k < 16; ++k) {
      float4 a = *(const float4*)&aT[k][rb];
      float4 w = *(const float4*)&wS[k][cb];
      acc[0][0] += a.x * w.x; acc[0][1] += a.x * w.y; acc[0][2] += a.x * w.z; acc[0][3] += a.x * w.w;
      acc[1][0] += a.y * w.x; acc[1][1] += a.y * w.y; acc[1][2] += a.y * w.z; acc[1][3] += a.y * w.w;
      acc[2][0] += a.z * w.x; acc[2][1] += a.z * w.y; acc[2][2] += a.z * w.z; acc[2][3] += a.z * w.w;
      acc[3][0] += a.w * w.x; acc[3][1] += a.w * w.y; acc[3][2] += a.w * w.z; acc[3][3] += a.w * w.w;
    }
#pragma unroll
    for (int i = 0; i < 4; ++i)
      *(float4*)(C + (size_t)(rb + i) * 64 + cb) =
          make_float4(acc[i][0], acc[i][1], acc[i][2], acc[i][3]);
  } else if (b < 1120) {  // ---- Kh/Vh = {K,V} @ {Wk,Wv}[l], 128-row tiles ----
    int tid = b - 320;
    int gy = tid / 100, rt = tid % 100;
    int which = gy >> 2, l = gy & 3;
    const float* A = (which ? Vin : Kin) + (size_t)rt * 128 * 64;
    const float* W = (which ? Wv : Wk) + l * 4096;
    float* C = (which ? Vh : Kh) + ((size_t)l * MKV + rt * 128) * 64;
    for (int i = t; i < 2048; i += 256) {  // 128 rows x 16 float4, transpose
      int r = i >> 4, c0 = (i & 15) * 4;
      float4 v = *(const float4*)(A + r * 64 + c0);
      aT[c0 + 0][r] = v.x; aT[c0 + 1][r] = v.y;
      aT[c0 + 2][r] = v.z; aT[c0 + 3][r] = v.w;
    }
    for (int i = t; i < 1024; i += 256) {
      float4 v = ((const float4*)W)[i];
      *(float4*)&wS[i >> 4][(i & 15) * 4] = v;
    }
    __syncthreads();
    const int rb = (t >> 4) * 8, cb = (t & 15) * 4;
    float acc[8][4] = {};
#pragma unroll 4
    for (int k = 0; k < 64; ++k) {
      float4 a0 = *(const float4*)&aT[k][rb];
      float4 a1 = *(const float4*)&aT[k][rb + 4];
      float4 w = *(const float4*)&wS[k][cb];
      acc[0][0] += a0.x * w.x; acc[0][1] += a0.x * w.y; acc[0][2] += a0.x * w.z; acc[0][3] += a0.x * w.w;
      acc[1][0] += a0.y * w.x; acc[1][1] += a0.y * w.y; acc[1][2] += a0.y * w.z; acc[1][3] += a0.y * w.w;
      acc[2][0] += a0.z * w.x; acc[2][1] += a0.z * w.y; acc[2][2] += a0.z * w.z; acc[2][3] += a0.z * w.w;
      acc[3][0] += a0.w * w.x; acc[3][1] += a0.w * w.y; acc[3][2] += a0.w * w.z; acc[3][3] += a0.w * w.w;
      acc[4][0] += a1.x * w.x; acc[4][1] += a1.x * w.y; acc[4][2] += a1.x * w.z; acc[4][3] += a1.x * w.w;
      acc[5][0] += a1.y * w.x; acc[5][1] += a1.y * w.y; acc[5][2] += a1.y * w.z; acc[5][3] += a1.y * w.w;
      acc[6][0] += a1.z * w.x; acc[6][1] += a1.z * w.y; acc[6][2] += a1.z * w.z; acc[6][3] += a1.z * w.w;
      acc[7][0] += a1.w * w.x; acc[7][1] += a1.w * w.y; acc[7][2] += a1.w * w.z; acc[7][3] += a1.w * w.w;
    }
#pragma unroll
    for (int i = 0; i < 8; ++i)
      *(float4*)(C + (size_t)(rb + i) * 64 + cb) =
          make_float4(acc[i][0], acc[i][1], acc[i][2], acc[i][3]);
  } else {  // ---- zero agg (all layers) ----
    int i = (b - 1120) * 256 + t;
    float4 z = make_float4(0.f, 0.f, 0.f, 0.f);
    for (int j = i; j < NLAYERS * NATOMS * 16; j += 80 * 256)
      ((float4*)agg)[j] = z;
  }
}

// -- per layer: edge messages + scatter-add, AND init xout = xin (residual) ---
__global__ void edge_copy_kernel(const float* __restrict__ xin,
                                 const float* __restrict__ EWl,
                                 const int* __restrict__ src,
                                 const int* __restrict__ dst,
                                 float* __restrict__ agg,
                                 float* __restrict__ xout) {
  int idx = blockIdx.x * 256 + threadIdx.x;  // covers E*64 = 327680
  if (idx < NATOMS * 64) xout[idx] = xin[idx];
  int e = idx >> 6, f = idx & 63;
  float m = xin[src[e] * 64 + f] + EWl[idx];
  m = m / (1.f + __expf(-m));  // silu
  atomicAdd(&agg[dst[e] * 64 + f], m);
}

// -- fused attention, slim LDS (~50 KB -> 3 blocks/CU).
//    one block per (graph, head, q-quarter): 32*4*4 = 512 blocks x 512 thr ----
__global__ __launch_bounds__(512) void fused_attn_kernel(
    const float* __restrict__ xin, const float* __restrict__ agg,
    const float* __restrict__ Wm, const float* __restrict__ Wq,
    const float* __restrict__ Wo, const float* __restrict__ Kh,
    const float* __restrict__ Vh, float* __restrict__ xout) {
  __shared__ float hS[QH][64];
  __shared__ float Qs[QH][16];   // Q*0.25, later reused as o_head
  __shared__ float KT[16][404];  // K head-slice transposed [d][k], padded
  __shared__ float P[QH][400];
  __shared__ float part[8][QH][16];
  __shared__ float lsum[QH];

  const int g = blockIdx.x, hd = blockIdx.y, qq = blockIdx.z;
  const int t = threadIdx.x;
  const int hoff = hd * DHEAD;
  const int qbase = g * NPG + qq * QH;
  const int kbase = g * MPG;

  // h = xin + agg @ Wm  (agg rows read from global; lane-uniform -> broadcast)
  for (int i = t; i < QH * 64; i += 512) {
    int q = i >> 6, f = i & 63;
    const float* arow = agg + (qbase + q) * 64;
    float acc = xin[(qbase + q) * 64 + f];
#pragma unroll 16
    for (int k = 0; k < 64; ++k) acc += arow[k] * Wm[k * 64 + f];
    hS[q][f] = acc;
  }
  __syncthreads();

  // Q_head = (h @ Wq slice) * 0.25 ; stage K^T head-slice
  for (int i = t; i < QH * 16; i += 512) {
    int q = i >> 4, d = i & 15;
    float acc = 0.f;
#pragma unroll 16
    for (int k = 0; k < 64; ++k) acc += hS[q][k] * Wq[k * 64 + hoff + d];
    Qs[q][d] = acc * 0.25f;
  }
  for (int i = t; i < MPG * DHEAD; i += 512) {
    int k = i >> 4, d = i & 15;
    KT[d][k] = Kh[(size_t)(kbase + k) * 64 + hoff + d];
  }
  __syncthreads();

  // scores: P[q][k], lane-consecutive k (stride-1 LDS, conflict-free)
  for (int i = t; i < QH * MPG; i += 512) {
    int q = i / MPG, k = i - q * MPG;
    float acc = 0.f;
#pragma unroll
    for (int d = 0; d < DHEAD; ++d) acc += Qs[q][d] * KT[d][k];
    P[q][k] = acc;
  }
  __syncthreads();

  // softmax rows (unnormalized exp + row sum); 8 waves over 10 rows
  {
    const int w = t >> 6, lane = t & 63;
    for (int q = w; q < QH; q += 8) {
      float mx = -1e30f;
      for (int k = lane; k < MPG; k += 64) mx = fmaxf(mx, P[q][k]);
      for (int off = 32; off; off >>= 1) mx = fmaxf(mx, __shfl_xor(mx, off));
      float s = 0.f;
      for (int k = lane; k < MPG; k += 64) {
        float p = __expf(P[q][k] - mx);
        P[q][k] = p;
        s += p;
      }
      for (int off = 32; off; off >>= 1) s += __shfl_xor(s, off);
      if (lane == 0) lsum[q] = s;
    }
  }
  __syncthreads();

  // PV: 8-way k-split; V read from global (L2-resident)
  {
    const int ks = t >> 6, j = t & 63, k0 = ks * 50;
    for (int pair = j; pair < QH * 16; pair += 64) {
      int q = pair >> 4, d = pair & 15;
      float acc = 0.f;
#pragma unroll 5
      for (int k = k0; k < k0 + 50; ++k)
        acc += P[q][k] * Vh[(size_t)(kbase + k) * 64 + hoff + d];
      part[ks][q][d] = acc;
    }
  }
  __syncthreads();

  // reduce partials + normalize -> reuse Qs as o_head
  if (t < QH * 16) {
    int q = t >> 4, d = t & 15;
    float o = 0.f;
#pragma unroll
    for (int ks = 0; ks < 8; ++ks) o += part[ks][q][d];
    Qs[q][d] = o / lsum[q];
  }
  __syncthreads();

  // out-projection partial for this head -> atomicAdd into xout
  for (int i = t; i < QH * 64; i += 512) {
    int q = i >> 6, f = i & 63;
    float acc = 0.f;
#pragma unroll
    for (int d = 0; d < DHEAD; ++d) acc += Qs[q][d] * Wo[(hoff + d) * 64 + f];
    atomicAdd(&xout[(qbase + q) * 64 + f], acc);
  }
}

extern "C" void kernel_launch(void* const* d_in, const int* in_sizes, int n_in,
                              void* d_out, int out_size, void* d_ws, size_t ws_size,
                              hipStream_t stream) {
  const float* x        = (const float*)d_in[0];
  const float* edge_attr= (const float*)d_in[1];
  const float* K        = (const float*)d_in[2];
  const float* V        = (const float*)d_in[3];
  const float* We       = (const float*)d_in[4];
  const float* Wm       = (const float*)d_in[5];
  const float* Wq       = (const float*)d_in[6];
  const float* Wk       = (const float*)d_in[7];
  const float* Wv       = (const float*)d_in[8];
  const float* Wo       = (const float*)d_in[9];
  const int*   eidx     = (const int*)d_in[10];
  const int*   src      = eidx;
  const int*   dst      = eidx + EEDGE;

  float* w    = (float*)d_ws;
  float* Kh   = w;                                   // 4*12800*64
  float* Vh   = Kh + (size_t)NLAYERS * MKV * 64;     // 4*12800*64
  float* EW   = Vh + (size_t)NLAYERS * MKV * 64;     // 4*5120*64
  float* agg  = EW + (size_t)NLAYERS * EEDGE * 64;   // 4*1280*64
  float* xA   = agg + (size_t)NLAYERS * NATOMS * 64;
  float* xB   = xA + NATOMS * 64;

  // one precompute kernel: agg zero + EW + Kh/Vh (all layers)
  precompute_kernel<<<1200, 256, 0, stream>>>(edge_attr, K, V, We, Wk, Wv,
                                              EW, Kh, Vh, agg);

  const float* xin = x;
  for (int l = 0; l < NLAYERS; ++l) {
    float* aggl = agg + (size_t)l * NATOMS * 64;
    float* xout = (l == NLAYERS - 1) ? (float*)d_out : ((l & 1) ? xB : xA);
    edge_copy_kernel<<<EEDGE * 64 / 256, 256, 0, stream>>>(
        xin, EW + (size_t)l * EEDGE * 64, src, dst, aggl, xout);
    fused_attn_kernel<<<dim3(NGRAPH, NHEAD, 4), 512, 0, stream>>>(
        xin, aggl, Wm + l * 4096, Wq + l * 4096, Wo + l * 4096,
        Kh + (size_t)l * MKV * 64, Vh + (size_t)l * MKV * 64, xout);
    xin = xout;
  }
}

// Round 8
// 123.826 us; speedup vs baseline: 1.1255x; 1.1255x over previous
//
#include <hip/hip_runtime.h>
#include <hip/hip_bf16.h>
#include <math.h>

#define NATOMS 1280
#define NHEAD 4
#define DHEAD 16
#define EEDGE 5120
#define MKV 12800
#define NLAYERS 4
#define NGRAPH 32
#define NPG 40      // atoms per graph
#define MPG 400     // kv per graph
#define QH 10       // q rows per attention block (quarter graph)

// ---- one precompute kernel: agg zero + EW GEMM + KV GEMM --------------------
// blocks [0,320): EW tiles; [320,1120): KV tiles; [1120,1200): agg zeroing
__global__ __launch_bounds__(256) void precompute_kernel(
    const float* __restrict__ edge_attr, const float* __restrict__ Kin,
    const float* __restrict__ Vin, const float* __restrict__ We,
    const float* __restrict__ Wk, const float* __restrict__ Wv,
    float* __restrict__ EW, float* __restrict__ Kh, float* __restrict__ Vh,
    float* __restrict__ agg) {
  __shared__ float aT[64][132];  // A tile transposed [k][row], padded
  __shared__ float wS[64][64];
  const int b = blockIdx.x, t = threadIdx.x;

  if (b < 320) {  // ---- EW[l] = edge_attr @ We[l], 64-row tiles, K=16 ----
    int l = b / 80, et = b % 80;
    const float* A = edge_attr + (size_t)et * 64 * 16;
    const float* W = We + l * 1024;
    float* C = EW + ((size_t)l * EEDGE + et * 64) * 64;
    {
      int r = t >> 2, c0 = (t & 3) * 4;
      float4 v = *(const float4*)(A + r * 16 + c0);
      aT[c0 + 0][r] = v.x; aT[c0 + 1][r] = v.y;
      aT[c0 + 2][r] = v.z; aT[c0 + 3][r] = v.w;
      float4 w = ((const float4*)W)[t];
      *(float4*)&wS[t >> 4][(t & 15) * 4] = w;
    }
    __syncthreads();
    const int rb = (t >> 4) * 4, cb = (t & 15) * 4;
    float acc[4][4] = {};
#pragma unroll
    for (int k = 0; k < 16; ++k) {
      float4 a = *(const float4*)&aT[k][rb];
      float4 w = *(const float4*)&wS[k][cb];
      acc[0][0] += a.x * w.x; acc[0][1] += a.x * w.y; acc[0][2] += a.x * w.z; acc[0][3] += a.x * w.w;
      acc[1][0] += a.y * w.x; acc[1][1] += a.y * w.y; acc[1][2] += a.y * w.z; acc[1][3] += a.y * w.w;
      acc[2][0] += a.z * w.x; acc[2][1] += a.z * w.y; acc[2][2] += a.z * w.z; acc[2][3] += a.z * w.w;
      acc[3][0] += a.w * w.x; acc[3][1] += a.w * w.y; acc[3][2] += a.w * w.z; acc[3][3] += a.w * w.w;
    }
#pragma unroll
    for (int i = 0; i < 4; ++i)
      *(float4*)(C + (size_t)(rb + i) * 64 + cb) =
          make_float4(acc[i][0], acc[i][1], acc[i][2], acc[i][3]);
  } else if (b < 1120) {  // ---- Kh/Vh = {K,V} @ {Wk,Wv}[l], 128-row tiles ----
    int tid = b - 320;
    int gy = tid / 100, rt = tid % 100;
    int which = gy >> 2, l = gy & 3;
    const float* A = (which ? Vin : Kin) + (size_t)rt * 128 * 64;
    const float* W = (which ? Wv : Wk) + l * 4096;
    float* C = (which ? Vh : Kh) + ((size_t)l * MKV + rt * 128) * 64;
    for (int i = t; i < 2048; i += 256) {  // 128 rows x 16 float4, transpose
      int r = i >> 4, c0 = (i & 15) * 4;
      float4 v = *(const float4*)(A + r * 64 + c0);
      aT[c0 + 0][r] = v.x; aT[c0 + 1][r] = v.y;
      aT[c0 + 2][r] = v.z; aT[c0 + 3][r] = v.w;
    }
    for (int i = t; i < 1024; i += 256) {
      float4 v = ((const float4*)W)[i];
      *(float4*)&wS[i >> 4][(i & 15) * 4] = v;
    }
    __syncthreads();
    const int rb = (t >> 4) * 8, cb = (t & 15) * 4;
    float acc[8][4] = {};
#pragma unroll 4
    for (int k = 0; k < 64; ++k) {
      float4 a0 = *(const float4*)&aT[k][rb];
      float4 a1 = *(const float4*)&aT[k][rb + 4];
      float4 w = *(const float4*)&wS[k][cb];
      acc[0][0] += a0.x * w.x; acc[0][1] += a0.x * w.y; acc[0][2] += a0.x * w.z; acc[0][3] += a0.x * w.w;
      acc[1][0] += a0.y * w.x; acc[1][1] += a0.y * w.y; acc[1][2] += a0.y * w.z; acc[1][3] += a0.y * w.w;
      acc[2][0] += a0.z * w.x; acc[2][1] += a0.z * w.y; acc[2][2] += a0.z * w.z; acc[2][3] += a0.z * w.w;
      acc[3][0] += a0.w * w.x; acc[3][1] += a0.w * w.y; acc[3][2] += a0.w * w.z; acc[3][3] += a0.w * w.w;
      acc[4][0] += a1.x * w.x; acc[4][1] += a1.x * w.y; acc[4][2] += a1.x * w.z; acc[4][3] += a1.x * w.w;
      acc[5][0] += a1.y * w.x; acc[5][1] += a1.y * w.y; acc[5][2] += a1.y * w.z; acc[5][3] += a1.y * w.w;
      acc[6][0] += a1.z * w.x; acc[6][1] += a1.z * w.y; acc[6][2] += a1.z * w.z; acc[6][3] += a1.z * w.w;
      acc[7][0] += a1.w * w.x; acc[7][1] += a1.w * w.y; acc[7][2] += a1.w * w.z; acc[7][3] += a1.w * w.w;
    }
#pragma unroll
    for (int i = 0; i < 8; ++i)
      *(float4*)(C + (size_t)(rb + i) * 64 + cb) =
          make_float4(acc[i][0], acc[i][1], acc[i][2], acc[i][3]);
  } else {  // ---- zero agg (all layers) ----
    int i = (b - 1120) * 256 + t;
    float4 z = make_float4(0.f, 0.f, 0.f, 0.f);
    for (int j = i; j < NLAYERS * NATOMS * 16; j += 80 * 256)
      ((float4*)agg)[j] = z;
  }
}

// -- per layer: edge messages + scatter-add, AND init xout = xin (residual) ---
__global__ void edge_copy_kernel(const float* __restrict__ xin,
                                 const float* __restrict__ EWl,
                                 const int* __restrict__ src,
                                 const int* __restrict__ dst,
                                 float* __restrict__ agg,
                                 float* __restrict__ xout) {
  int idx = blockIdx.x * 256 + threadIdx.x;  // covers E*64 = 327680
  if (idx < NATOMS * 64) xout[idx] = xin[idx];
  int e = idx >> 6, f = idx & 63;
  float m = xin[src[e] * 64 + f] + EWl[idx];
  m = m / (1.f + __expf(-m));  // silu
  atomicAdd(&agg[dst[e] * 64 + f], m);
}

// -- fused attention. Row-major padded K/V (conflict-free), 74.4 KB LDS ->
//    2 blocks/CU; grid (32,4,4) = 512 blocks x 512 threads => all CUs 2-deep --
__global__ __launch_bounds__(512) void fused_attn_kernel(
    const float* __restrict__ xin, const float* __restrict__ agg,
    const float* __restrict__ Wm, const float* __restrict__ Wq,
    const float* __restrict__ Wo, const float* __restrict__ Kh,
    const float* __restrict__ Vh, float* __restrict__ xout) {
  __shared__ union {
    float hS[QH][64];            // live: phase1-2
    float P[QH][MPG];            // live: phase3+
  } u;
  __shared__ float Qs[QH][16];   // Q*0.25, later reused as o_head
  __shared__ float Ks[MPG][17];  // K head-slice row-major, +1 pad
  __shared__ float Vs[MPG][17];
  __shared__ float part[8][QH][16];
  __shared__ float lsum[QH];

  const int g = blockIdx.x, hd = blockIdx.y, qq = blockIdx.z;
  const int t = threadIdx.x;
  const int hoff = hd * DHEAD;
  const int qbase = g * NPG + qq * QH;
  const int kbase = g * MPG;

  // phase 1: stage K,V head-slices + h GEMM (all independent)
  for (int i = t; i < MPG * DHEAD; i += 512) {
    int k = i >> 4, d = i & 15;  // 16-lane groups: 64B-coalesced global reads
    Ks[k][d] = Kh[(size_t)(kbase + k) * 64 + hoff + d];
    Vs[k][d] = Vh[(size_t)(kbase + k) * 64 + hoff + d];
  }
  for (int i = t; i < QH * 64; i += 512) {
    int q = i >> 6, f = i & 63;
    const float* arow = agg + (qbase + q) * 64;
    float acc = xin[(qbase + q) * 64 + f];
#pragma unroll 16
    for (int k = 0; k < 64; ++k) acc += arow[k] * Wm[k * 64 + f];
    u.hS[q][f] = acc;
  }
  __syncthreads();

  // phase 2: Q_head = (h @ Wq slice) * 0.25
  if (t < QH * 16) {
    int q = t >> 4, d = t & 15;
    float acc = 0.f;
#pragma unroll 16
    for (int k = 0; k < 64; ++k) acc += u.hS[q][k] * Wq[k * 64 + hoff + d];
    Qs[q][d] = acc * 0.25f;
  }
  __syncthreads();

  // phase 3: scores P[q][k] (Ks reads stride-17: 2 lanes/bank = free)
  for (int i = t; i < QH * MPG; i += 512) {
    int q = i / MPG, k = i - q * MPG;
    float acc = 0.f;
#pragma unroll
    for (int d = 0; d < DHEAD; ++d) acc += Qs[q][d] * Ks[k][d];
    u.P[q][k] = acc;
  }
  __syncthreads();

  // phase 4: softmax rows (unnormalized exp + row sum); 8 waves over 10 rows
  {
    const int w = t >> 6, lane = t & 63;
    for (int q = w; q < QH; q += 8) {
      float mx = -1e30f;
      for (int k = lane; k < MPG; k += 64) mx = fmaxf(mx, u.P[q][k]);
      for (int off = 32; off; off >>= 1) mx = fmaxf(mx, __shfl_xor(mx, off));
      float s = 0.f;
      for (int k = lane; k < MPG; k += 64) {
        float p = __expf(u.P[q][k] - mx);
        u.P[q][k] = p;
        s += p;
      }
      for (int off = 32; off; off >>= 1) s += __shfl_xor(s, off);
      if (lane == 0) lsum[q] = s;
    }
  }
  __syncthreads();

  // phase 5: PV, 8-way k-split (Vs reads are same-address broadcasts)
  {
    const int ks = t >> 6, j = t & 63, k0 = ks * 50;
    for (int pair = j; pair < QH * 16; pair += 64) {
      int q = pair >> 4, d = pair & 15;
      float acc = 0.f;
#pragma unroll 5
      for (int k = k0; k < k0 + 50; ++k) acc += u.P[q][k] * Vs[k][d];
      part[ks][q][d] = acc;
    }
  }
  __syncthreads();

  // phase 6: reduce partials + normalize -> reuse Qs as o_head
  if (t < QH * 16) {
    int q = t >> 4, d = t & 15;
    float o = 0.f;
#pragma unroll
    for (int ks = 0; ks < 8; ++ks) o += part[ks][q][d];
    Qs[q][d] = o / lsum[q];
  }
  __syncthreads();

  // phase 7: out-projection partial for this head -> atomicAdd into xout
  for (int i = t; i < QH * 64; i += 512) {
    int q = i >> 6, f = i & 63;
    float acc = 0.f;
#pragma unroll
    for (int d = 0; d < DHEAD; ++d) acc += Qs[q][d] * Wo[(hoff + d) * 64 + f];
    atomicAdd(&xout[(qbase + q) * 64 + f], acc);
  }
}

extern "C" void kernel_launch(void* const* d_in, const int* in_sizes, int n_in,
                              void* d_out, int out_size, void* d_ws, size_t ws_size,
                              hipStream_t stream) {
  const float* x        = (const float*)d_in[0];
  const float* edge_attr= (const float*)d_in[1];
  const float* K        = (const float*)d_in[2];
  const float* V        = (const float*)d_in[3];
  const float* We       = (const float*)d_in[4];
  const float* Wm       = (const float*)d_in[5];
  const float* Wq       = (const float*)d_in[6];
  const float* Wk       = (const float*)d_in[7];
  const float* Wv       = (const float*)d_in[8];
  const float* Wo       = (const float*)d_in[9];
  const int*   eidx     = (const int*)d_in[10];
  const int*   src      = eidx;
  const int*   dst      = eidx + EEDGE;

  float* w    = (float*)d_ws;
  float* Kh   = w;                                   // 4*12800*64
  float* Vh   = Kh + (size_t)NLAYERS * MKV * 64;     // 4*12800*64
  float* EW   = Vh + (size_t)NLAYERS * MKV * 64;     // 4*5120*64
  float* agg  = EW + (size_t)NLAYERS * EEDGE * 64;   // 4*1280*64
  float* xA   = agg + (size_t)NLAYERS * NATOMS * 64;
  float* xB   = xA + NATOMS * 64;

  // one precompute kernel: agg zero + EW + Kh/Vh (all layers)
  precompute_kernel<<<1200, 256, 0, stream>>>(edge_attr, K, V, We, Wk, Wv,
                                              EW, Kh, Vh, agg);

  const float* xin = x;
  for (int l = 0; l < NLAYERS; ++l) {
    float* aggl = agg + (size_t)l * NATOMS * 64;
    float* xout = (l == NLAYERS - 1) ? (float*)d_out : ((l & 1) ? xB : xA);
    edge_copy_kernel<<<EEDGE * 64 / 256, 256, 0, stream>>>(
        xin, EW + (size_t)l * EEDGE * 64, src, dst, aggl, xout);
    fused_attn_kernel<<<dim3(NGRAPH, NHEAD, 4), 512, 0, stream>>>(
        xin, aggl, Wm + l * 4096, Wq + l * 4096, Wo + l * 4096,
        Kh + (size_t)l * MKV * 64, Vh + (size_t)l * MKV * 64, xout);
    xin = xout;
  }
}